// Round 5
// baseline (6406.915 us; speedup 1.0000x reference)
//
#include <hip/hip_runtime.h>
#include <hip/hip_bf16.h>
#include <math.h>

typedef __hip_bfloat16 bf16;
typedef __attribute__((ext_vector_type(8))) short bf16x8;   // 8 bf16 in 4 VGPRs
typedef __attribute__((ext_vector_type(4))) float f32x4;

// ---------- load/store helpers (mixed f32/bf16) ----------
__device__ __forceinline__ float ldf(const float* p, size_t i) { return p[i]; }
__device__ __forceinline__ float ldf(const bf16*  p, size_t i) { return __bfloat162float(p[i]); }
__device__ __forceinline__ void  stf(float* p, size_t i, float v) { p[i] = v; }
__device__ __forceinline__ void  stf(bf16*  p, size_t i, float v) { p[i] = __float2bfloat16(v); }
__device__ __forceinline__ unsigned short f2b(float f) {
    bf16 h = __float2bfloat16(f);
    return *reinterpret_cast<unsigned short*>(&h);
}

// ---------- 1. sim = image_feat[16,256] @ text_queue[256,57600] ----------
__global__ __launch_bounds__(256) void sim_kernel(const float* __restrict__ img,
                                                  const float* __restrict__ tq,
                                                  float* __restrict__ sim) {
    __shared__ float simg[16][256];
    int tid = threadIdx.x;
    for (int i = tid; i < 16 * 256; i += 256) simg[i >> 8][i & 255] = img[i];
    __syncthreads();
    int j = blockIdx.x * 256 + tid;               // 57600 = 225*256 exact
    float acc[16];
#pragma unroll
    for (int r = 0; r < 16; ++r) acc[r] = 0.f;
    for (int e = 0; e < 256; ++e) {
        float t = tq[(size_t)e * 57600 + j];
#pragma unroll
        for (int r = 0; r < 16; ++r) acc[r] += simg[r][e] * t;
    }
#pragma unroll
    for (int r = 0; r < 16; ++r) sim[(size_t)r * 57600 + j] = acc[r];
}

// ---------- 2. top-16 per row + softmax weights ----------
__global__ __launch_bounds__(256) void topk_kernel(const float* __restrict__ sim,
                                                   int* __restrict__ out_idx,
                                                   float* __restrict__ out_w) {
    int b = blockIdx.x, tid = threadIdx.x;
    __shared__ float svals[256];
    __shared__ int   sidx[256];
    __shared__ int   sel[16];
    __shared__ float selv[16];
    const float* row = sim + (size_t)b * 57600;
    for (int kk = 0; kk < 16; ++kk) {
        float best = -1e30f; int bi = 0x7fffffff;
        for (int j = tid; j < 57600; j += 256) {
            bool skip = false;
            for (int t = 0; t < kk; ++t) if (sel[t] == j) skip = true;
            if (skip) continue;
            float v = row[j];
            if (v > best || (v == best && j < bi)) { best = v; bi = j; }
        }
        svals[tid] = best; sidx[tid] = bi;
        __syncthreads();
        for (int off = 128; off > 0; off >>= 1) {
            if (tid < off) {
                float v2 = svals[tid + off]; int i2 = sidx[tid + off];
                if (v2 > svals[tid] || (v2 == svals[tid] && i2 < sidx[tid])) { svals[tid] = v2; sidx[tid] = i2; }
            }
            __syncthreads();
        }
        if (tid == 0) { sel[kk] = sidx[0]; selv[kk] = svals[0]; }
        __syncthreads();
    }
    if (tid == 0) {
        float mx = selv[0], e[16], sum = 0.f;
        for (int t = 0; t < 16; ++t) { e[t] = expf(selv[t] - mx); sum += e[t]; }
        for (int t = 0; t < 16; ++t) { out_idx[b * 16 + t] = sel[t]; out_w[b * 16 + t] = e[t] / sum; }
    }
}

// ---------- 3. gather embeddings + pos, gather mask (one 64-seq chunk) ----------
__global__ __launch_bounds__(256) void embed_kernel(const int* __restrict__ topk_idx,
                                                    const int* __restrict__ ids_queue,
                                                    const float* __restrict__ emb,
                                                    const float* __restrict__ pos,
                                                    const float* __restrict__ mask_queue,
                                                    bf16* __restrict__ h0,
                                                    float* __restrict__ msk,
                                                    int row0) {
    int r = blockIdx.x, l = blockIdx.y, tid = threadIdx.x;
    int gr = row0 + r;
    int q = topk_idx[gr];
    int id = ids_queue[(size_t)q * 90 + l];
    if (tid == 0) msk[gr * 90 + l] = mask_queue[(size_t)q * 90 + l];
    size_t ob = ((size_t)(r * 90 + l)) * 768;
#pragma unroll
    for (int u = 0; u < 3; ++u) {
        int d = tid + u * 256;
        h0[ob + d] = __float2bfloat16(emb[(size_t)id * 768 + d] + pos[(size_t)l * 768 + d]);
    }
}

// ---------- MFMA GEMM body: C = act(A@B) (+ R), bf16 A, f32 B (cvt), f32 accum ----------
// 128x128 tile / block; 4 waves 2x2; each wave 64x64 = 4x4 frags of 16x16x32.
// LDS: As[128][32] bf16 (A rows), Bs[128][32] bf16 (B TRANSPOSED: Bs[n][k]); both
// XOR-swizzled: 16B-slot ^= (row>>1)&3 to kill the stride-64B bank conflict (G4).
// k-order inside the 32-wide fragment is a shared bijection for A and B, so the
// dot product is exact regardless of the HW's internal k map (perm-invariance).
// ACT: 0 none, 1 gelu(tanh), 2 relu.  Requires K%32==0, N%128==0; M guarded.
template<int ACT, bool RES, typename OT, typename RT>
__device__ __forceinline__ void gemm_body(const bf16* __restrict__ A,
                                          const float* __restrict__ B,
                                          OT* __restrict__ C,
                                          const RT* __restrict__ R,
                                          int M, int N, int K, int ldb) {
    __shared__ __align__(16) unsigned int As4[128 * 16];  // 8 KB
    __shared__ __align__(16) unsigned int Bs4[128 * 16];  // 8 KB
    const int tid = threadIdx.x;
    const int lane = tid & 63, w = tid >> 6;
    const int wr = w >> 1, wc = w & 1;
    const int m0 = blockIdx.y * 128, n0 = blockIdx.x * 128;
    const int l16 = lane & 15, kgrp = lane >> 4;

    f32x4 acc[4][4];
    const f32x4 zero4 = {0.f, 0.f, 0.f, 0.f};
#pragma unroll
    for (int i = 0; i < 4; ++i)
#pragma unroll
        for (int j = 0; j < 4; ++j) acc[i][j] = zero4;

    const int arow = tid >> 1;             // A staging: row 0..127
    const int aslot0 = (tid & 1) * 2;      // two 16B slots per thread
    const int kp = tid >> 4;               // B staging: k-pair 0..15
    const int nch = tid & 15;              // n-chunk of 8

    for (int kt = 0; kt < K; kt += 32) {
        // ---- stage A: 128x32 bf16, row-major, swizzled slots ----
        {
            int gm = m0 + arow;
#pragma unroll
            for (int s = 0; s < 2; ++s) {
                int slot = aslot0 + s;
                uint4 val = make_uint4(0u, 0u, 0u, 0u);
                if (gm < M)
                    val = *reinterpret_cast<const uint4*>(A + (size_t)gm * K + kt + slot * 8);
                int sw = slot ^ ((arow >> 1) & 3);
                *reinterpret_cast<uint4*>(&As4[arow * 16 + sw * 4]) = val;
            }
        }
        // ---- stage B transposed: Bs[n][k], cvt f32->bf16, swizzled ----
        {
            const float* b0 = B + (size_t)(kt + 2 * kp) * ldb + n0 + nch * 8;
            const float* b1 = b0 + ldb;
            float4 p0 = *reinterpret_cast<const float4*>(b0);
            float4 p1 = *reinterpret_cast<const float4*>(b0 + 4);
            float4 q0 = *reinterpret_cast<const float4*>(b1);
            float4 q1 = *reinterpret_cast<const float4*>(b1 + 4);
            float r0[8] = {p0.x, p0.y, p0.z, p0.w, p1.x, p1.y, p1.z, p1.w};
            float r1[8] = {q0.x, q0.y, q0.z, q0.w, q1.x, q1.y, q1.z, q1.w};
#pragma unroll
            for (int j = 0; j < 8; ++j) {
                int n = nch * 8 + j;
                unsigned int u = (unsigned int)f2b(r0[j]) | ((unsigned int)f2b(r1[j]) << 16);
                int slot = (kp >> 2) ^ ((n >> 1) & 3);
                Bs4[n * 16 + slot * 4 + (kp & 3)] = u;
            }
        }
        __syncthreads();
        // ---- fragments + 16 MFMA ----
        bf16x8 af[4], bfv[4];
#pragma unroll
        for (int mi = 0; mi < 4; ++mi) {
            int row = wr * 64 + mi * 16 + l16;
            int slot = kgrp ^ ((row >> 1) & 3);
            af[mi] = *reinterpret_cast<const bf16x8*>(&As4[row * 16 + slot * 4]);
        }
#pragma unroll
        for (int ni = 0; ni < 4; ++ni) {
            int col = wc * 64 + ni * 16 + l16;
            int slot = kgrp ^ ((col >> 1) & 3);
            bfv[ni] = *reinterpret_cast<const bf16x8*>(&Bs4[col * 16 + slot * 4]);
        }
#pragma unroll
        for (int mi = 0; mi < 4; ++mi)
#pragma unroll
            for (int ni = 0; ni < 4; ++ni)
                acc[mi][ni] = __builtin_amdgcn_mfma_f32_16x16x32_bf16(af[mi], bfv[ni], acc[mi][ni], 0, 0, 0);
        __syncthreads();
    }
    // ---- epilogue: D row = (lane>>4)*4+r, col = lane&15 (m89-verified) ----
    const int l4 = (lane >> 4) * 4;
#pragma unroll
    for (int mi = 0; mi < 4; ++mi) {
        int rowb = m0 + wr * 64 + mi * 16 + l4;
#pragma unroll
        for (int ni = 0; ni < 4; ++ni) {
            int col = n0 + wc * 64 + ni * 16 + l16;
            f32x4 a = acc[mi][ni];
#pragma unroll
            for (int r = 0; r < 4; ++r) {
                int row = rowb + r;
                if (row < M) {
                    float v = a[r];
                    if (ACT == 1) {
                        float t = 0.7978845608028654f * (v + 0.044715f * v * v * v);
                        v = 0.5f * v * (1.0f + tanhf(t));
                    } else if (ACT == 2) {
                        v = fmaxf(v, 0.0f);
                    }
                    if (RES) v += ldf(R, (size_t)row * N + col);
                    stf(C, (size_t)row * N + col, v);
                }
            }
        }
    }
}

template<int ACT, bool RES, typename OT, typename RT>
__global__ __launch_bounds__(256) void gemm_mfma(const bf16* __restrict__ A,
                                                 const float* __restrict__ B,
                                                 OT* __restrict__ C,
                                                 const RT* __restrict__ R,
                                                 int M, int N, int K, int ldb) {
    gemm_body<ACT, RES, OT, RT>(A, B, C, R, M, N, K, ldb);
}

// fused multi-head projection: blockIdx.z picks (B,C) pair; N=K=768, ldb=768
__global__ __launch_bounds__(256) void gemm_qkv(const bf16* __restrict__ A,
                                                const float* __restrict__ B0,
                                                const float* __restrict__ B1,
                                                const float* __restrict__ B2,
                                                bf16* __restrict__ C0,
                                                bf16* __restrict__ C1,
                                                bf16* __restrict__ C2,
                                                int M) {
    const float* B = (blockIdx.z == 0) ? B0 : (blockIdx.z == 1 ? B1 : B2);
    bf16* C = (blockIdx.z == 0) ? C0 : (blockIdx.z == 1 ? C1 : C2);
    gemm_body<0, false, bf16, float>(A, B, C, (const float*)nullptr, M, 768, 768, 768);
}

// ---------- LayerNorm (no affine), rows of 768; safe in-place ----------
template<typename InT, typename OutT>
__global__ __launch_bounds__(256) void ln_kernel(const InT* __restrict__ in, OutT* __restrict__ out) {
    const size_t row = blockIdx.x;
    const int tid = threadIdx.x;
    const InT* p = in + row * 768;
    float x[3], s = 0.f, ss = 0.f;
#pragma unroll
    for (int u = 0; u < 3; ++u) { x[u] = ldf(p, tid + u * 256); s += x[u]; ss += x[u] * x[u]; }
#pragma unroll
    for (int off = 32; off > 0; off >>= 1) { s += __shfl_down(s, off, 64); ss += __shfl_down(ss, off, 64); }
    __shared__ float rs_[4], rss_[4], stats[2];
    const int wid = tid >> 6, lane = tid & 63;
    if (lane == 0) { rs_[wid] = s; rss_[wid] = ss; }
    __syncthreads();
    if (tid == 0) {
        float S = rs_[0] + rs_[1] + rs_[2] + rs_[3];
        float SS = rss_[0] + rss_[1] + rss_[2] + rss_[3];
        float mean = S * (1.f / 768.f);
        float var = SS * (1.f / 768.f) - mean * mean;
        stats[0] = mean; stats[1] = rsqrtf(var + 1e-6f);
    }
    __syncthreads();
    float mean = stats[0], rstd = stats[1];
    OutT* q = out + row * 768;
#pragma unroll
    for (int u = 0; u < 3; ++u) stf(q, tid + u * 256, (x[u] - mean) * rstd);
}

// ---------- fused attention row kernel: scores+softmax+PV ----------
template<bool MASKED>
__global__ __launch_bounds__(128) void fused_attn(const bf16* __restrict__ Qb,
                                                  const bf16* __restrict__ Kb,
                                                  const bf16* __restrict__ Vb,
                                                  bf16* __restrict__ Ctx,
                                                  const float* __restrict__ mask,
                                                  int Nq, int Nk, float scale) {
    int bh = blockIdx.x, i = blockIdx.y, tid = threadIdx.x;
    int item = bh / 6, h = bh % 6;
    __shared__ float qv[128];
    __shared__ float p[224];
    __shared__ float red[128];
    qv[tid] = __bfloat162float(Qb[((size_t)(item * Nq + i)) * 768 + h * 128 + tid]);
    __syncthreads();
    for (int j = tid; j < Nk; j += 128) {
        const bf16* kp = Kb + ((size_t)(item * Nk + j)) * 768 + h * 128;
        float acc = 0.f;
        for (int d = 0; d < 128; ++d) acc += qv[d] * __bfloat162float(kp[d]);
        acc *= scale;
        if (MASKED && mask[item * Nk + j] <= 0.f) acc = -1e9f;
        p[j] = acc;
    }
    __syncthreads();
    float m = -1e30f;
    for (int j = tid; j < Nk; j += 128) m = fmaxf(m, p[j]);
    red[tid] = m; __syncthreads();
    for (int off = 64; off > 0; off >>= 1) { if (tid < off) red[tid] = fmaxf(red[tid], red[tid + off]); __syncthreads(); }
    m = red[0]; __syncthreads();
    float s = 0.f;
    for (int j = tid; j < Nk; j += 128) { float e = expf(p[j] - m); p[j] = e; s += e; }
    red[tid] = s; __syncthreads();
    for (int off = 64; off > 0; off >>= 1) { if (tid < off) red[tid] += red[tid + off]; __syncthreads(); }
    float inv = 1.f / red[0];
    int d = tid;
    float acc = 0.f;
    for (int j = 0; j < Nk; ++j) acc += p[j] * __bfloat162float(Vb[((size_t)(item * Nk + j)) * 768 + h * 128 + d]);
    Ctx[((size_t)(item * Nq + i)) * 768 + h * 128 + d] = __float2bfloat16(acc * inv);
}

// ---------- per-k weighted sum (one chunk of 4 batch items) ----------
__global__ __launch_bounds__(256) void wsum_kernel(const bf16* __restrict__ h2,
                                                   const float* __restrict__ w,
                                                   bf16* __restrict__ finalB,
                                                   int b0) {
    int b = blockIdx.x, l = blockIdx.y, tid = threadIdx.x;
    __shared__ float ws_[16];
    if (tid < 16) ws_[tid] = w[(b0 + b) * 16 + tid];
    __syncthreads();
#pragma unroll
    for (int u = 0; u < 3; ++u) {
        int d = tid + u * 256;
        float acc = 0.f;
        for (int kk = 0; kk < 16; ++kk)
            acc += ws_[kk] * __bfloat162float(h2[(((size_t)(b * 16 + kk)) * 90 + l) * 768 + d]);
        finalB[((size_t)((b0 + b) * 90 + l)) * 768 + d] = __float2bfloat16(acc);
    }
}

__global__ void copy_f32(const float* __restrict__ in, float* __restrict__ o, int n) {
    int i = blockIdx.x * blockDim.x + threadIdx.x;
    if (i < n) o[i] = in[i];
}

// ---------- host ----------
extern "C" void kernel_launch(void* const* d_in, const int* in_sizes, int n_in,
                              void* d_out, int out_size, void* d_ws, size_t ws_size,
                              hipStream_t stream) {
    (void)in_sizes; (void)n_in; (void)out_size; (void)ws_size;
    const float* image_feat   = (const float*)d_in[0];
    const float* image_embeds = (const float*)d_in[1];
    const float* text_queue   = (const float*)d_in[2];
    const float* mask_queue   = (const float*)d_in[3];
    const float* emb_table    = (const float*)d_in[4];
    const float* pos_emb      = (const float*)d_in[5];
    const float* enc_wq       = (const float*)d_in[6];
    const float* enc_wk       = (const float*)d_in[7];
    const float* enc_wv       = (const float*)d_in[8];
    const float* enc_wo       = (const float*)d_in[9];
    const float* enc_w1       = (const float*)d_in[10];
    const float* enc_w2       = (const float*)d_in[11];
    const float* dec_self_w   = (const float*)d_in[12];
    const float* dec_cross_w  = (const float*)d_in[13];
    const float* dec_w1       = (const float*)d_in[14];
    const float* dec_w2       = (const float*)d_in[15];
    const int*   ids_queue    = (const int*)d_in[16];
    float* out = (float*)d_out;

    char* ws = (char*)d_ws;
    size_t off = 0;
    auto alloc = [&](size_t b) { size_t o = off; off += (b + 255) & ~(size_t)255; return o; };

    int*   topk_idx = (int*)  (ws + alloc(256 * 4));
    float* topk_w   = (float*)(ws + alloc(256 * 4));
    float* msk      = (float*)(ws + alloc(256 * 90 * 4));
    bf16*  finalB   = (bf16*) (ws + alloc((size_t)1440 * 768 * 2));

    const size_t SZ_HC = (size_t)5760 * 768 * 2;   // 8,847,360 B (64-seq chunk, bf16)
    size_t a0 = alloc(SZ_HC * 6);                  // 53.1 MB arena (total ws ~= 55.4 MB)
    bf16*  h0c = (bf16*)(ws + a0);                 // slot 0
    bf16*  qc  = (bf16*)(ws + a0 + SZ_HC);         // slot 1
    bf16*  kc  = (bf16*)(ws + a0 + SZ_HC * 2);     // slot 2
    bf16*  vc  = (bf16*)(ws + a0 + SZ_HC * 3);     // slot 3
    bf16*  cxc = (bf16*)(ws + a0 + SZ_HC * 4);     // slot 4
    float* t2  = (float*)(ws + a0 + SZ_HC * 4);    // f32, slots 4-5 (cxc+vc... NO: 4+5 = cxc + slot5)
    float* simp = (float*)(ws + a0);               // sim [16,57600] f32, dead before encoder

    // decoder overlay (arena fully dead after finalB is built)
    size_t dd = a0;
    auto dal = [&](size_t b) { size_t o = dd; dd += (b + 255) & ~(size_t)255; return o; };
    float* xp  = (float*)(ws + dal((size_t)3152 * 768 * 4));
    bf16*  xnp = (bf16*) (ws + dal((size_t)3152 * 768 * 2));
    bf16*  dqp = (bf16*) (ws + dal((size_t)3152 * 768 * 2));
    bf16*  dkp = (bf16*) (ws + dal((size_t)3152 * 768 * 2));
    bf16*  dvp = (bf16*) (ws + dal((size_t)3152 * 768 * 2));
    bf16*  dcp = (bf16*) (ws + dal((size_t)3152 * 768 * 2));
    bf16*  dfp = (bf16*) (ws + dal((size_t)3152 * 1024 * 2));  // ends ~40.3 MB < arena

    const float scale = 0.08838834764831845f;  // 1/sqrt(128)
    const float* nof = nullptr;

    // ---- retrieval ----
    sim_kernel<<<225, 256, 0, stream>>>(image_feat, text_queue, simp);
    topk_kernel<<<16, 256, 0, stream>>>(simp, topk_idx, topk_w);

    // ---- knowledge encoder: 4 chunks of 64 sequences ----
    // per-chunk liveness (slot): h0=0 -> q/k/v=1/2/3 -> ctx=4 -> t1=2 -> h1=1
    //   -> FF1-out=0 (per c) -> t2(f32)=4+5 (R: h1=1 at c0, else t2) -> h2=2
    // t2 spans slots 4-5 which are both dead after t1 (ctx consumed, v consumed).
    for (int ch = 0; ch < 4; ++ch) {
        int row0 = ch * 64;
        embed_kernel<<<dim3(64, 90), 256, 0, stream>>>(topk_idx, ids_queue, emb_table, pos_emb,
                                                       mask_queue, h0c, msk, row0);
        dim3 gP(6, 45);  // 768/128 x 5760/128
        gemm_qkv<<<dim3(6, 45, 3), 256, 0, stream>>>(h0c, enc_wq, enc_wk, enc_wv, qc, kc, vc, 5760);
        fused_attn<true><<<dim3(384, 90), 128, 0, stream>>>(qc, kc, vc, cxc, msk + row0 * 90, 90, 90, scale);
        // t1 = ctx@wo + h0  -> kc (slot 2); frees h0c, qc, vc, cxc
        gemm_mfma<0, true, bf16, bf16><<<gP, 256, 0, stream>>>(cxc, enc_wo, kc, h0c, 5760, 768, 768, 768);
        ln_kernel<bf16, bf16><<<5760, 256, 0, stream>>>(kc, qc);  // h1 -> qc (slot 1)
        // FF chunked over the 3072 dim; FF1 chunk -> h0c; t2 f32 accumulates in slots 4-5
        for (int c = 0; c < 4; ++c) {
            gemm_mfma<1, false, bf16, float><<<gP, 256, 0, stream>>>(
                qc, enc_w1 + (size_t)c * 768, h0c, nof, 5760, 768, 768, 3072);
            if (c == 0)
                gemm_mfma<0, true, float, bf16><<<gP, 256, 0, stream>>>(
                    h0c, enc_w2 + (size_t)c * 768 * 768, t2, qc, 5760, 768, 768, 768);
            else
                gemm_mfma<0, true, float, float><<<gP, 256, 0, stream>>>(
                    h0c, enc_w2 + (size_t)c * 768 * 768, t2, t2, 5760, 768, 768, 768);
        }
        ln_kernel<float, bf16><<<5760, 256, 0, stream>>>(t2, kc);  // h2 -> kc
        wsum_kernel<<<dim3(4, 90), 256, 0, stream>>>(kc, topk_w, finalB, ch * 4);
    }

    // ---- decoder ----
    copy_f32<<<(2420736 + 255) / 256, 256, 0, stream>>>(image_embeds, xp, 2420736);
    for (int l = 0; l < 2; ++l) {
        const float* sw = dec_self_w + (size_t)l * 4 * 589824;
        const float* cw = dec_cross_w + (size_t)l * 4 * 589824;
        const float* w1 = dec_w1 + (size_t)l * 768 * 1024;
        const float* w2 = dec_w2 + (size_t)l * 1024 * 768;
        dim3 gD(6, 25);   // 768/128 x ceil(3152/128)
        dim3 gFF(8, 25);  // 1024/128 x ceil(3152/128)

        // self-attention sublayer
        ln_kernel<float, bf16><<<3152, 256, 0, stream>>>(xp, xnp);
        gemm_qkv<<<dim3(6, 25, 3), 256, 0, stream>>>(xnp, sw, sw + 589824, sw + 2 * 589824,
                                                     dqp, dkp, dvp, 3152);
        fused_attn<false><<<dim3(96, 197), 128, 0, stream>>>(dqp, dkp, dvp, dcp, nof, 197, 197, scale);
        gemm_mfma<0, true, float, float><<<gD, 256, 0, stream>>>(dcp, sw + 3 * 589824, xp, xp, 3152, 768, 768, 768);

        // cross-attention sublayer (K/V from finalB)
        ln_kernel<float, bf16><<<3152, 256, 0, stream>>>(xp, xnp);
        gemm_mfma<0, false, bf16, float><<<gD, 256, 0, stream>>>(xnp, cw, dqp, nof, 3152, 768, 768, 768);
        gemm_qkv<<<dim3(6, 12, 2), 256, 0, stream>>>(finalB, cw + 589824, cw + 2 * 589824, cw + 2 * 589824,
                                                     dkp, dvp, dvp, 1440);
        fused_attn<false><<<dim3(96, 197), 128, 0, stream>>>(dqp, dkp, dvp, dcp, nof, 197, 90, scale);
        gemm_mfma<0, true, float, float><<<gD, 256, 0, stream>>>(dcp, cw + 3 * 589824, xp, xp, 3152, 768, 768, 768);

        // FF sublayer (ReLU)
        ln_kernel<float, bf16><<<3152, 256, 0, stream>>>(xp, xnp);
        gemm_mfma<2, false, bf16, float><<<gFF, 256, 0, stream>>>(xnp, w1, dfp, nof, 3152, 1024, 768, 1024);
        gemm_mfma<0, true, float, float><<<gD, 256, 0, stream>>>(dfp, w2, xp, xp, 3152, 768, 1024, 768);
    }
    ln_kernel<float, float><<<3152, 256, 0, stream>>>(xp, out);
}

// Round 6
// 4257.731 us; speedup vs baseline: 1.5048x; 1.5048x over previous
//
#include <hip/hip_runtime.h>
#include <hip/hip_bf16.h>
#include <math.h>

typedef __hip_bfloat16 bf16;
typedef __attribute__((ext_vector_type(8))) short bf16x8;   // 8 bf16 in 4 VGPRs
typedef __attribute__((ext_vector_type(4))) float f32x4;

// ---------- load/store helpers (mixed f32/bf16) ----------
__device__ __forceinline__ float ldf(const float* p, size_t i) { return p[i]; }
__device__ __forceinline__ float ldf(const bf16*  p, size_t i) { return __bfloat162float(p[i]); }
__device__ __forceinline__ void  stf(float* p, size_t i, float v) { p[i] = v; }
__device__ __forceinline__ void  stf(bf16*  p, size_t i, float v) { p[i] = __float2bfloat16(v); }
__device__ __forceinline__ unsigned short f2b(float f) {
    bf16 h = __float2bfloat16(f);
    return *reinterpret_cast<unsigned short*>(&h);
}

// ---------- 1. sim = image_feat[16,256] @ text_queue[256,57600] ----------
__global__ __launch_bounds__(256) void sim_kernel(const float* __restrict__ img,
                                                  const float* __restrict__ tq,
                                                  float* __restrict__ sim) {
    __shared__ float simg[16][256];
    int tid = threadIdx.x;
    for (int i = tid; i < 16 * 256; i += 256) simg[i >> 8][i & 255] = img[i];
    __syncthreads();
    int j = blockIdx.x * 256 + tid;               // 57600 = 225*256 exact
    float acc[16];
#pragma unroll
    for (int r = 0; r < 16; ++r) acc[r] = 0.f;
    for (int e = 0; e < 256; ++e) {
        float t = tq[(size_t)e * 57600 + j];
#pragma unroll
        for (int r = 0; r < 16; ++r) acc[r] += simg[r][e] * t;
    }
#pragma unroll
    for (int r = 0; r < 16; ++r) sim[(size_t)r * 57600 + j] = acc[r];
}

// ---------- 2a. local top-16 per (row, 960-chunk): 60 chunks x 16 rows ----------
// Any global-top-16 element is in its chunk's local top-16 under the same
// total order (v desc, global idx asc), so the 60x16 candidate union suffices.
__global__ __launch_bounds__(256) void topk_local(const float* __restrict__ sim,
                                                  float* __restrict__ cand_v,
                                                  int* __restrict__ cand_i) {
    const int chunk = blockIdx.x, row = blockIdx.y, tid = threadIdx.x;
    __shared__ float vals[960];
    __shared__ float rv[256];
    __shared__ int   rs[256];
    const float* p = sim + (size_t)row * 57600 + chunk * 960;
    for (int s = tid; s < 960; s += 256) vals[s] = p[s];
    __syncthreads();
    for (int kk = 0; kk < 16; ++kk) {
        float bv = -1e30f; int bs = 0x7fffffff;
        for (int s = tid; s < 960; s += 256) {
            float v = vals[s];
            if (v > bv || (v == bv && s < bs)) { bv = v; bs = s; }
        }
        rv[tid] = bv; rs[tid] = bs;
        __syncthreads();
        for (int off2 = 128; off2 > 0; off2 >>= 1) {
            if (tid < off2) {
                float v2 = rv[tid + off2]; int s2 = rs[tid + off2];
                if (v2 > rv[tid] || (v2 == rv[tid] && s2 < rs[tid])) { rv[tid] = v2; rs[tid] = s2; }
            }
            __syncthreads();
        }
        if (tid == 0) {
            int s = rs[0];
            cand_v[((size_t)row * 60 + chunk) * 16 + kk] = rv[0];
            cand_i[((size_t)row * 60 + chunk) * 16 + kk] = chunk * 960 + s;
            vals[s] = -1e30f;  // remove winner
        }
        __syncthreads();
    }
}

// ---------- 2b. merge 960 candidates per row -> global top-16 + softmax ----------
__global__ __launch_bounds__(256) void topk_final(const float* __restrict__ cand_v,
                                                  const int* __restrict__ cand_i,
                                                  int* __restrict__ out_idx,
                                                  float* __restrict__ out_w) {
    const int row = blockIdx.x, tid = threadIdx.x;
    __shared__ float vals[960];
    __shared__ int   gidx[960];
    __shared__ float rv[256];
    __shared__ int   ri[256];
    __shared__ int   rs[256];
    __shared__ float selv[16];
    __shared__ int   seli[16];
    const float* pv = cand_v + (size_t)row * 960;
    const int*   pi = cand_i + (size_t)row * 960;
    for (int s = tid; s < 960; s += 256) { vals[s] = pv[s]; gidx[s] = pi[s]; }
    __syncthreads();
    for (int kk = 0; kk < 16; ++kk) {
        float bv = -1e30f; int bi = 0x7fffffff; int bs = 0;
        for (int s = tid; s < 960; s += 256) {
            float v = vals[s]; int g = gidx[s];
            if (v > bv || (v == bv && g < bi)) { bv = v; bi = g; bs = s; }
        }
        rv[tid] = bv; ri[tid] = bi; rs[tid] = bs;
        __syncthreads();
        for (int off2 = 128; off2 > 0; off2 >>= 1) {
            if (tid < off2) {
                float v2 = rv[tid + off2]; int i2 = ri[tid + off2]; int s2 = rs[tid + off2];
                if (v2 > rv[tid] || (v2 == rv[tid] && i2 < ri[tid])) { rv[tid] = v2; ri[tid] = i2; rs[tid] = s2; }
            }
            __syncthreads();
        }
        if (tid == 0) {
            selv[kk] = rv[0]; seli[kk] = ri[0];
            vals[rs[0]] = -1e30f;
        }
        __syncthreads();
    }
    if (tid == 0) {
        float mx = selv[0], e[16], sum = 0.f;
        for (int t = 0; t < 16; ++t) { e[t] = expf(selv[t] - mx); sum += e[t]; }
        for (int t = 0; t < 16; ++t) { out_idx[row * 16 + t] = seli[t]; out_w[row * 16 + t] = e[t] / sum; }
    }
}

// ---------- 3. gather embeddings + pos, gather mask (one 64-seq chunk) ----------
__global__ __launch_bounds__(256) void embed_kernel(const int* __restrict__ topk_idx,
                                                    const int* __restrict__ ids_queue,
                                                    const float* __restrict__ emb,
                                                    const float* __restrict__ pos,
                                                    const float* __restrict__ mask_queue,
                                                    bf16* __restrict__ h0,
                                                    float* __restrict__ msk,
                                                    int row0) {
    int r = blockIdx.x, l = blockIdx.y, tid = threadIdx.x;
    int gr = row0 + r;
    int q = topk_idx[gr];
    int id = ids_queue[(size_t)q * 90 + l];
    if (tid == 0) msk[gr * 90 + l] = mask_queue[(size_t)q * 90 + l];
    size_t ob = ((size_t)(r * 90 + l)) * 768;
#pragma unroll
    for (int u = 0; u < 3; ++u) {
        int d = tid + u * 256;
        h0[ob + d] = __float2bfloat16(emb[(size_t)id * 768 + d] + pos[(size_t)l * 768 + d]);
    }
}

// ---------- MFMA GEMM body: C = act(A@B) (+ R), bf16 A, f32 B (cvt), f32 accum ----------
// 128x128 tile / block; 4 waves 2x2; each wave 64x64 = 4x4 frags of 16x16x32.
// LDS: As[128][32] bf16 (A rows), Bs[128][32] bf16 (B TRANSPOSED: Bs[n][k]); both
// XOR-swizzled: 16B-slot ^= (row>>1)&3 to kill the stride-64B bank conflict (G4).
// k-order inside the 32-wide fragment is a shared bijection for A and B, so the
// dot product is exact regardless of the HW's internal k map (perm-invariance).
// ACT: 0 none, 1 gelu(tanh), 2 relu.  Requires K%32==0, N%128==0; M guarded.
template<int ACT, bool RES, typename OT, typename RT>
__device__ __forceinline__ void gemm_body(const bf16* __restrict__ A,
                                          const float* __restrict__ B,
                                          OT* __restrict__ C,
                                          const RT* __restrict__ R,
                                          int M, int N, int K, int ldb) {
    __shared__ __align__(16) unsigned int As4[128 * 16];  // 8 KB
    __shared__ __align__(16) unsigned int Bs4[128 * 16];  // 8 KB
    const int tid = threadIdx.x;
    const int lane = tid & 63, w = tid >> 6;
    const int wr = w >> 1, wc = w & 1;
    const int m0 = blockIdx.y * 128, n0 = blockIdx.x * 128;
    const int l16 = lane & 15, kgrp = lane >> 4;

    f32x4 acc[4][4];
    const f32x4 zero4 = {0.f, 0.f, 0.f, 0.f};
#pragma unroll
    for (int i = 0; i < 4; ++i)
#pragma unroll
        for (int j = 0; j < 4; ++j) acc[i][j] = zero4;

    const int arow = tid >> 1;             // A staging: row 0..127
    const int aslot0 = (tid & 1) * 2;      // two 16B slots per thread
    const int kp = tid >> 4;               // B staging: k-pair 0..15
    const int nch = tid & 15;              // n-chunk of 8

    for (int kt = 0; kt < K; kt += 32) {
        // ---- stage A: 128x32 bf16, row-major, swizzled slots ----
        {
            int gm = m0 + arow;
#pragma unroll
            for (int s = 0; s < 2; ++s) {
                int slot = aslot0 + s;
                uint4 val = make_uint4(0u, 0u, 0u, 0u);
                if (gm < M)
                    val = *reinterpret_cast<const uint4*>(A + (size_t)gm * K + kt + slot * 8);
                int sw = slot ^ ((arow >> 1) & 3);
                *reinterpret_cast<uint4*>(&As4[arow * 16 + sw * 4]) = val;
            }
        }
        // ---- stage B transposed: Bs[n][k], cvt f32->bf16, swizzled ----
        {
            const float* b0 = B + (size_t)(kt + 2 * kp) * ldb + n0 + nch * 8;
            const float* b1 = b0 + ldb;
            float4 p0 = *reinterpret_cast<const float4*>(b0);
            float4 p1 = *reinterpret_cast<const float4*>(b0 + 4);
            float4 q0 = *reinterpret_cast<const float4*>(b1);
            float4 q1 = *reinterpret_cast<const float4*>(b1 + 4);
            float r0[8] = {p0.x, p0.y, p0.z, p0.w, p1.x, p1.y, p1.z, p1.w};
            float r1[8] = {q0.x, q0.y, q0.z, q0.w, q1.x, q1.y, q1.z, q1.w};
#pragma unroll
            for (int j = 0; j < 8; ++j) {
                int n = nch * 8 + j;
                unsigned int u = (unsigned int)f2b(r0[j]) | ((unsigned int)f2b(r1[j]) << 16);
                int slot = (kp >> 2) ^ ((n >> 1) & 3);
                Bs4[n * 16 + slot * 4 + (kp & 3)] = u;
            }
        }
        __syncthreads();
        // ---- fragments + 16 MFMA ----
        bf16x8 af[4], bfv[4];
#pragma unroll
        for (int mi = 0; mi < 4; ++mi) {
            int row = wr * 64 + mi * 16 + l16;
            int slot = kgrp ^ ((row >> 1) & 3);
            af[mi] = *reinterpret_cast<const bf16x8*>(&As4[row * 16 + slot * 4]);
        }
#pragma unroll
        for (int ni = 0; ni < 4; ++ni) {
            int col = wc * 64 + ni * 16 + l16;
            int slot = kgrp ^ ((col >> 1) & 3);
            bfv[ni] = *reinterpret_cast<const bf16x8*>(&Bs4[col * 16 + slot * 4]);
        }
#pragma unroll
        for (int mi = 0; mi < 4; ++mi)
#pragma unroll
            for (int ni = 0; ni < 4; ++ni)
                acc[mi][ni] = __builtin_amdgcn_mfma_f32_16x16x32_bf16(af[mi], bfv[ni], acc[mi][ni], 0, 0, 0);
        __syncthreads();
    }
    // ---- epilogue: D row = (lane>>4)*4+r, col = lane&15 (m89-verified) ----
    const int l4 = (lane >> 4) * 4;
#pragma unroll
    for (int mi = 0; mi < 4; ++mi) {
        int rowb = m0 + wr * 64 + mi * 16 + l4;
#pragma unroll
        for (int ni = 0; ni < 4; ++ni) {
            int col = n0 + wc * 64 + ni * 16 + l16;
            f32x4 a = acc[mi][ni];
#pragma unroll
            for (int r = 0; r < 4; ++r) {
                int row = rowb + r;
                if (row < M) {
                    float v = a[r];
                    if (ACT == 1) {
                        float t = 0.7978845608028654f * (v + 0.044715f * v * v * v);
                        v = 0.5f * v * (1.0f + tanhf(t));
                    } else if (ACT == 2) {
                        v = fmaxf(v, 0.0f);
                    }
                    if (RES) v += ldf(R, (size_t)row * N + col);
                    stf(C, (size_t)row * N + col, v);
                }
            }
        }
    }
}

template<int ACT, bool RES, typename OT, typename RT>
__global__ __launch_bounds__(256) void gemm_mfma(const bf16* __restrict__ A,
                                                 const float* __restrict__ B,
                                                 OT* __restrict__ C,
                                                 const RT* __restrict__ R,
                                                 int M, int N, int K, int ldb) {
    gemm_body<ACT, RES, OT, RT>(A, B, C, R, M, N, K, ldb);
}

// fused multi-head projection: blockIdx.z picks (B,C) pair; N=K=768, ldb=768
__global__ __launch_bounds__(256) void gemm_qkv(const bf16* __restrict__ A,
                                                const float* __restrict__ B0,
                                                const float* __restrict__ B1,
                                                const float* __restrict__ B2,
                                                bf16* __restrict__ C0,
                                                bf16* __restrict__ C1,
                                                bf16* __restrict__ C2,
                                                int M) {
    const float* B = (blockIdx.z == 0) ? B0 : (blockIdx.z == 1 ? B1 : B2);
    bf16* C = (blockIdx.z == 0) ? C0 : (blockIdx.z == 1 ? C1 : C2);
    gemm_body<0, false, bf16, float>(A, B, C, (const float*)nullptr, M, 768, 768, 768);
}

// ---------- LayerNorm (no affine), rows of 768; safe in-place ----------
template<typename InT, typename OutT>
__global__ __launch_bounds__(256) void ln_kernel(const InT* __restrict__ in, OutT* __restrict__ out) {
    const size_t row = blockIdx.x;
    const int tid = threadIdx.x;
    const InT* p = in + row * 768;
    float x[3], s = 0.f, ss = 0.f;
#pragma unroll
    for (int u = 0; u < 3; ++u) { x[u] = ldf(p, tid + u * 256); s += x[u]; ss += x[u] * x[u]; }
#pragma unroll
    for (int off = 32; off > 0; off >>= 1) { s += __shfl_down(s, off, 64); ss += __shfl_down(ss, off, 64); }
    __shared__ float rs_[4], rss_[4], stats[2];
    const int wid = tid >> 6, lane = tid & 63;
    if (lane == 0) { rs_[wid] = s; rss_[wid] = ss; }
    __syncthreads();
    if (tid == 0) {
        float S = rs_[0] + rs_[1] + rs_[2] + rs_[3];
        float SS = rss_[0] + rss_[1] + rss_[2] + rss_[3];
        float mean = S * (1.f / 768.f);
        float var = SS * (1.f / 768.f) - mean * mean;
        stats[0] = mean; stats[1] = rsqrtf(var + 1e-6f);
    }
    __syncthreads();
    float mean = stats[0], rstd = stats[1];
    OutT* q = out + row * 768;
#pragma unroll
    for (int u = 0; u < 3; ++u) stf(q, tid + u * 256, (x[u] - mean) * rstd);
}

// ---------- fused attention row kernel: scores+softmax+PV ----------
template<bool MASKED>
__global__ __launch_bounds__(128) void fused_attn(const bf16* __restrict__ Qb,
                                                  const bf16* __restrict__ Kb,
                                                  const bf16* __restrict__ Vb,
                                                  bf16* __restrict__ Ctx,
                                                  const float* __restrict__ mask,
                                                  int Nq, int Nk, float scale) {
    int bh = blockIdx.x, i = blockIdx.y, tid = threadIdx.x;
    int item = bh / 6, h = bh % 6;
    __shared__ float qv[128];
    __shared__ float p[224];
    __shared__ float red[128];
    qv[tid] = __bfloat162float(Qb[((size_t)(item * Nq + i)) * 768 + h * 128 + tid]);
    __syncthreads();
    for (int j = tid; j < Nk; j += 128) {
        const bf16* kp = Kb + ((size_t)(item * Nk + j)) * 768 + h * 128;
        float acc = 0.f;
        for (int d = 0; d < 128; ++d) acc += qv[d] * __bfloat162float(kp[d]);
        acc *= scale;
        if (MASKED && mask[item * Nk + j] <= 0.f) acc = -1e9f;
        p[j] = acc;
    }
    __syncthreads();
    float m = -1e30f;
    for (int j = tid; j < Nk; j += 128) m = fmaxf(m, p[j]);
    red[tid] = m; __syncthreads();
    for (int off = 64; off > 0; off >>= 1) { if (tid < off) red[tid] = fmaxf(red[tid], red[tid + off]); __syncthreads(); }
    m = red[0]; __syncthreads();
    float s = 0.f;
    for (int j = tid; j < Nk; j += 128) { float e = expf(p[j] - m); p[j] = e; s += e; }
    red[tid] = s; __syncthreads();
    for (int off = 64; off > 0; off >>= 1) { if (tid < off) red[tid] += red[tid + off]; __syncthreads(); }
    float inv = 1.f / red[0];
    int d = tid;
    float acc = 0.f;
    for (int j = 0; j < Nk; ++j) acc += p[j] * __bfloat162float(Vb[((size_t)(item * Nk + j)) * 768 + h * 128 + d]);
    Ctx[((size_t)(item * Nq + i)) * 768 + h * 128 + d] = __float2bfloat16(acc * inv);
}

// ---------- per-k weighted sum (one chunk of 4 batch items) ----------
__global__ __launch_bounds__(256) void wsum_kernel(const bf16* __restrict__ h2,
                                                   const float* __restrict__ w,
                                                   bf16* __restrict__ finalB,
                                                   int b0) {
    int b = blockIdx.x, l = blockIdx.y, tid = threadIdx.x;
    __shared__ float ws_[16];
    if (tid < 16) ws_[tid] = w[(b0 + b) * 16 + tid];
    __syncthreads();
#pragma unroll
    for (int u = 0; u < 3; ++u) {
        int d = tid + u * 256;
        float acc = 0.f;
        for (int kk = 0; kk < 16; ++kk)
            acc += ws_[kk] * __bfloat162float(h2[(((size_t)(b * 16 + kk)) * 90 + l) * 768 + d]);
        finalB[((size_t)((b0 + b) * 90 + l)) * 768 + d] = __float2bfloat16(acc);
    }
}

__global__ void copy_f32(const float* __restrict__ in, float* __restrict__ o, int n) {
    int i = blockIdx.x * blockDim.x + threadIdx.x;
    if (i < n) o[i] = in[i];
}

// ---------- host ----------
extern "C" void kernel_launch(void* const* d_in, const int* in_sizes, int n_in,
                              void* d_out, int out_size, void* d_ws, size_t ws_size,
                              hipStream_t stream) {
    (void)in_sizes; (void)n_in; (void)out_size; (void)ws_size;
    const float* image_feat   = (const float*)d_in[0];
    const float* image_embeds = (const float*)d_in[1];
    const float* text_queue   = (const float*)d_in[2];
    const float* mask_queue   = (const float*)d_in[3];
    const float* emb_table    = (const float*)d_in[4];
    const float* pos_emb      = (const float*)d_in[5];
    const float* enc_wq       = (const float*)d_in[6];
    const float* enc_wk       = (const float*)d_in[7];
    const float* enc_wv       = (const float*)d_in[8];
    const float* enc_wo       = (const float*)d_in[9];
    const float* enc_w1       = (const float*)d_in[10];
    const float* enc_w2       = (const float*)d_in[11];
    const float* dec_self_w   = (const float*)d_in[12];
    const float* dec_cross_w  = (const float*)d_in[13];
    const float* dec_w1       = (const float*)d_in[14];
    const float* dec_w2       = (const float*)d_in[15];
    const int*   ids_queue    = (const int*)d_in[16];
    float* out = (float*)d_out;

    char* ws = (char*)d_ws;
    size_t off = 0;
    auto alloc = [&](size_t b) { size_t o = off; off += (b + 255) & ~(size_t)255; return o; };

    int*   topk_idx = (int*)  (ws + alloc(256 * 4));
    float* topk_w   = (float*)(ws + alloc(256 * 4));
    float* msk      = (float*)(ws + alloc(256 * 90 * 4));
    float* cand_v   = (float*)(ws + alloc(16 * 960 * 4));
    int*   cand_i   = (int*)  (ws + alloc(16 * 960 * 4));
    bf16*  finalB   = (bf16*) (ws + alloc((size_t)1440 * 768 * 2));

    const size_t SZ_HC = (size_t)5760 * 768 * 2;   // 8,847,360 B (64-seq chunk, bf16)
    size_t a0 = alloc(SZ_HC * 6);                  // 53.1 MB arena (total ws ~= 55.5 MB)
    bf16*  h0c = (bf16*)(ws + a0);                 // slot 0
    bf16*  qc  = (bf16*)(ws + a0 + SZ_HC);         // slot 1
    bf16*  kc  = (bf16*)(ws + a0 + SZ_HC * 2);     // slot 2
    bf16*  vc  = (bf16*)(ws + a0 + SZ_HC * 3);     // slot 3
    bf16*  cxc = (bf16*)(ws + a0 + SZ_HC * 4);     // slot 4
    float* t2  = (float*)(ws + a0 + SZ_HC * 4);    // f32, spans slots 4-5
    float* simp = (float*)(ws + a0);               // sim [16,57600] f32, dead before encoder

    // decoder overlay (arena fully dead after finalB is built)
    size_t dd = a0;
    auto dal = [&](size_t b) { size_t o = dd; dd += (b + 255) & ~(size_t)255; return o; };
    float* xp  = (float*)(ws + dal((size_t)3152 * 768 * 4));
    bf16*  xnp = (bf16*) (ws + dal((size_t)3152 * 768 * 2));
    bf16*  dqp = (bf16*) (ws + dal((size_t)3152 * 768 * 2));
    bf16*  dkp = (bf16*) (ws + dal((size_t)3152 * 768 * 2));
    bf16*  dvp = (bf16*) (ws + dal((size_t)3152 * 768 * 2));
    bf16*  dcp = (bf16*) (ws + dal((size_t)3152 * 768 * 2));
    bf16*  dfp = (bf16*) (ws + dal((size_t)3152 * 1024 * 2));  // ends ~40.3 MB < arena

    const float scale = 0.08838834764831845f;  // 1/sqrt(128)
    const float* nof = nullptr;

    // ---- retrieval ----
    sim_kernel<<<225, 256, 0, stream>>>(image_feat, text_queue, simp);
    topk_local<<<dim3(60, 16), 256, 0, stream>>>(simp, cand_v, cand_i);
    topk_final<<<16, 256, 0, stream>>>(cand_v, cand_i, topk_idx, topk_w);

    // ---- knowledge encoder: 4 chunks of 64 sequences ----
    // per-chunk liveness (slot): h0=0 -> q/k/v=1/2/3 -> ctx=4 -> t1=2 -> h1=1
    //   -> FF1-out=0 (per c) -> t2(f32)=4+5 (R: h1=1 at c0, else t2) -> h2=2
    for (int ch = 0; ch < 4; ++ch) {
        int row0 = ch * 64;
        embed_kernel<<<dim3(64, 90), 256, 0, stream>>>(topk_idx, ids_queue, emb_table, pos_emb,
                                                       mask_queue, h0c, msk, row0);
        dim3 gP(6, 45);  // 768/128 x 5760/128
        gemm_qkv<<<dim3(6, 45, 3), 256, 0, stream>>>(h0c, enc_wq, enc_wk, enc_wv, qc, kc, vc, 5760);
        fused_attn<true><<<dim3(384, 90), 128, 0, stream>>>(qc, kc, vc, cxc, msk + row0 * 90, 90, 90, scale);
        // t1 = ctx@wo + h0  -> kc (slot 2); frees h0c, qc, vc, cxc
        gemm_mfma<0, true, bf16, bf16><<<gP, 256, 0, stream>>>(cxc, enc_wo, kc, h0c, 5760, 768, 768, 768);
        ln_kernel<bf16, bf16><<<5760, 256, 0, stream>>>(kc, qc);  // h1 -> qc (slot 1)
        // FF chunked over the 3072 dim; FF1 chunk -> h0c; t2 f32 accumulates in slots 4-5
        for (int c = 0; c < 4; ++c) {
            gemm_mfma<1, false, bf16, float><<<gP, 256, 0, stream>>>(
                qc, enc_w1 + (size_t)c * 768, h0c, nof, 5760, 768, 768, 3072);
            if (c == 0)
                gemm_mfma<0, true, float, bf16><<<gP, 256, 0, stream>>>(
                    h0c, enc_w2 + (size_t)c * 768 * 768, t2, qc, 5760, 768, 768, 768);
            else
                gemm_mfma<0, true, float, float><<<gP, 256, 0, stream>>>(
                    h0c, enc_w2 + (size_t)c * 768 * 768, t2, t2, 5760, 768, 768, 768);
        }
        ln_kernel<float, bf16><<<5760, 256, 0, stream>>>(t2, kc);  // h2 -> kc
        wsum_kernel<<<dim3(4, 90), 256, 0, stream>>>(kc, topk_w, finalB, ch * 4);
    }

    // ---- decoder ----
    copy_f32<<<(2420736 + 255) / 256, 256, 0, stream>>>(image_embeds, xp, 2420736);
    for (int l = 0; l < 2; ++l) {
        const float* sw = dec_self_w + (size_t)l * 4 * 589824;
        const float* cw = dec_cross_w + (size_t)l * 4 * 589824;
        const float* w1 = dec_w1 + (size_t)l * 768 * 1024;
        const float* w2 = dec_w2 + (size_t)l * 1024 * 768;
        dim3 gD(6, 25);   // 768/128 x ceil(3152/128)
        dim3 gFF(8, 25);  // 1024/128 x ceil(3152/128)

        // self-attention sublayer
        ln_kernel<float, bf16><<<3152, 256, 0, stream>>>(xp, xnp);
        gemm_qkv<<<dim3(6, 25, 3), 256, 0, stream>>>(xnp, sw, sw + 589824, sw + 2 * 589824,
                                                     dqp, dkp, dvp, 3152);
        fused_attn<false><<<dim3(96, 197), 128, 0, stream>>>(dqp, dkp, dvp, dcp, nof, 197, 197, scale);
        gemm_mfma<0, true, float, float><<<gD, 256, 0, stream>>>(dcp, sw + 3 * 589824, xp, xp, 3152, 768, 768, 768);

        // cross-attention sublayer (K/V from finalB)
        ln_kernel<float, bf16><<<3152, 256, 0, stream>>>(xp, xnp);
        gemm_mfma<0, false, bf16, float><<<gD, 256, 0, stream>>>(xnp, cw, dqp, nof, 3152, 768, 768, 768);
        gemm_qkv<<<dim3(6, 12, 2), 256, 0, stream>>>(finalB, cw + 589824, cw + 2 * 589824, cw + 2 * 589824,
                                                     dkp, dvp, dvp, 1440);
        fused_attn<false><<<dim3(96, 197), 128, 0, stream>>>(dqp, dkp, dvp, dcp, nof, 197, 90, scale);
        gemm_mfma<0, true, float, float><<<gD, 256, 0, stream>>>(dcp, cw + 3 * 589824, xp, xp, 3152, 768, 768, 768);

        // FF sublayer (ReLU)
        ln_kernel<float, bf16><<<3152, 256, 0, stream>>>(xp, xnp);
        gemm_mfma<2, false, bf16, float><<<gFF, 256, 0, stream>>>(xnp, w1, dfp, nof, 3152, 1024, 768, 1024);
        gemm_mfma<0, true, float, float><<<gD, 256, 0, stream>>>(dfp, w2, xp, xp, 3152, 768, 1024, 768);
    }
    ln_kernel<float, float><<<3152, 256, 0, stream>>>(xp, out);
}